// Round 1
// baseline (2468.880 us; speedup 1.0000x reference)
//
#include <hip/hip_runtime.h>

#define T_LEN 2048
#define C_DIM 1024

static __device__ __forceinline__ float sigf(float x) {
    return 1.f / (1.f + __expf(-x));
}

// ---------------------------------------------------------------------------
// NT GEMM: out[t,i] = sum_c A(t,c) * W[i,c];  A = mixv ? x + (shift-x)*mix : X
// 64x64 block tile, BK=16, 256 threads, 4x4 microtile.
// ---------------------------------------------------------------------------
__global__ __launch_bounds__(256) void gemm_nt(
    const float* __restrict__ X, const float* __restrict__ xprev,
    const float* __restrict__ mixv, const float* __restrict__ W,
    float* __restrict__ out)
{
    __shared__ __align__(16) float As[16][68];
    __shared__ __align__(16) float Ws[16][68];
    const int tid = threadIdx.x;
    const int t0 = blockIdx.y * 64;
    const int n0 = blockIdx.x * 64;
    const int lr = tid >> 2;            // 0..63 row in tile
    const int lk = (tid & 3) << 2;      // 0,4,8,12
    const int ty = tid >> 4;            // 0..15
    const int tx = tid & 15;            // 0..15
    float acc[4][4] = {{0.f}};

    const int trow = t0 + lr;
    const float* xrow  = X + (size_t)trow * C_DIM;
    const float* xprow = (trow == 0) ? xprev : (X + (size_t)(trow - 1) * C_DIM);
    const float* wrow  = W + (size_t)(n0 + lr) * C_DIM;

    for (int k0 = 0; k0 < C_DIM; k0 += 16) {
        float4 xv = *(const float4*)(xrow + k0 + lk);
        if (mixv) {
            float4 pv = *(const float4*)(xprow + k0 + lk);
            float4 mv = *(const float4*)(mixv + k0 + lk);
            xv.x += (pv.x - xv.x) * mv.x;
            xv.y += (pv.y - xv.y) * mv.y;
            xv.z += (pv.z - xv.z) * mv.z;
            xv.w += (pv.w - xv.w) * mv.w;
        }
        As[lk + 0][lr] = xv.x; As[lk + 1][lr] = xv.y;
        As[lk + 2][lr] = xv.z; As[lk + 3][lr] = xv.w;
        float4 wv = *(const float4*)(wrow + k0 + lk);
        Ws[lk + 0][lr] = wv.x; Ws[lk + 1][lr] = wv.y;
        Ws[lk + 2][lr] = wv.z; Ws[lk + 3][lr] = wv.w;
        __syncthreads();
#pragma unroll
        for (int kk = 0; kk < 16; ++kk) {
            float4 av = *(const float4*)&As[kk][ty << 2];
            float4 bv = *(const float4*)&Ws[kk][tx << 2];
            float a_[4] = {av.x, av.y, av.z, av.w};
            float b_[4] = {bv.x, bv.y, bv.z, bv.w};
#pragma unroll
            for (int i = 0; i < 4; ++i)
#pragma unroll
                for (int j = 0; j < 4; ++j)
                    acc[i][j] = fmaf(a_[i], b_[j], acc[i][j]);
        }
        __syncthreads();
    }
#pragma unroll
    for (int i = 0; i < 4; ++i) {
        float4 o4 = {acc[i][0], acc[i][1], acc[i][2], acc[i][3]};
        *(float4*)(out + (size_t)(t0 + (ty << 2) + i) * C_DIM + n0 + (tx << 2)) = o4;
    }
}

// ---------------------------------------------------------------------------
// LoRA stage 1: h[t,j] = act(sum_c A(t,c) * W1[c,j]),  Kh in {32,64,128}
// 256 threads, tpb = 256/Kh tokens per block.
// act: 0=none 1=tanh 2=sigmoid
// ---------------------------------------------------------------------------
__global__ __launch_bounds__(256) void lora1(
    const float* __restrict__ X, const float* __restrict__ xprev,
    const float* __restrict__ mixv, const float* __restrict__ W1,
    float* __restrict__ hbuf, int Kh, int act)
{
    __shared__ __align__(16) float As[8192];
    const int tid = threadIdx.x;
    const int tpb = 256 / Kh;
    const int t0 = blockIdx.x * tpb;
    for (int idx = tid; idx < (tpb << 10); idx += 256) {
        int l = idx >> 10, c = idx & 1023;
        int t = t0 + l;
        float xv = X[(size_t)t * C_DIM + c];
        float pv = (t == 0) ? xprev[c] : X[(size_t)(t - 1) * C_DIM + c];
        As[idx] = xv + (pv - xv) * mixv[c];
    }
    __syncthreads();
    const int l = tid / Kh;
    const int j = tid % Kh;
    const float* arow = As + (l << 10);
    float acc = 0.f;
#pragma unroll 4
    for (int c = 0; c < 1024; ++c)
        acc = fmaf(arow[c], W1[(size_t)c * Kh + j], acc);
    if (act == 1) acc = tanhf(acc);
    else if (act == 2) acc = sigf(acc);
    hbuf[(size_t)(t0 + l) * Kh + j] = acc;
}

// ---------------------------------------------------------------------------
// LoRA stage 2: z[t,i] = bias[i] + sum_j h[t,j]*W2[j,i], then per-mode epilogue
// mode 0 (w): out = exp(-e^{-0.5} * sigmoid(z))      [stores exp(w) directly]
// mode 1 (a): out = sigmoid(z)
// mode 2 (v): s = sigmoid(z); out = out + (vfirst - out)*s   (in-place on v)
// mode 3 (g): out = z
// ---------------------------------------------------------------------------
__global__ __launch_bounds__(256) void lora2(
    const float* __restrict__ hbuf, const float* __restrict__ W2,
    const float* __restrict__ bias, float* __restrict__ outp,
    const float* __restrict__ vfirst, int Kh, int mode)
{
    __shared__ __align__(16) float hs[128];
    const int t = blockIdx.y;
    const int i = blockIdx.x * 256 + threadIdx.x;
    if (threadIdx.x < Kh) hs[threadIdx.x] = hbuf[(size_t)t * Kh + threadIdx.x];
    __syncthreads();
    float acc = bias ? bias[i] : 0.f;
#pragma unroll 8
    for (int j = 0; j < Kh; ++j)
        acc = fmaf(hs[j], W2[(size_t)j * C_DIM + i], acc);
    const size_t idx = (size_t)t * C_DIM + i;
    if (mode == 0) {
        outp[idx] = __expf(-0.6065306597126334f * sigf(acc));
    } else if (mode == 1) {
        outp[idx] = sigf(acc);
    } else if (mode == 2) {
        float s = sigf(acc);
        float vr = outp[idx];
        outp[idx] = vr + (vfirst[idx] - vr) * s;
    } else {
        outp[idx] = acc;
    }
}

// ---------------------------------------------------------------------------
// k post-process: kk = normalize_per_head(k*k_k); bb = kk * a; k = k*(1+(a-1)*k_a)
// kB in-place, aB: reads a, writes bb (in-place). One token per block, 4 ch/thread.
// ---------------------------------------------------------------------------
__global__ __launch_bounds__(256) void kpost(
    float* __restrict__ kbuf, float* __restrict__ abuf, float* __restrict__ kkbuf,
    const float* __restrict__ k_k, const float* __restrict__ k_a)
{
    const int t = blockIdx.x, tid = threadIdx.x;
    const int c0 = tid << 2;
    const size_t base = (size_t)t * C_DIM + c0;
    float4 kr  = *(float4*)(kbuf + base);
    float4 kkw = *(const float4*)(k_k + c0);
    float4 kav = *(const float4*)(k_a + c0);
    float4 av  = *(float4*)(abuf + base);
    float4 kn = {kr.x * kkw.x, kr.y * kkw.y, kr.z * kkw.z, kr.w * kkw.w};
    float ss = kn.x * kn.x + kn.y * kn.y + kn.z * kn.z + kn.w * kn.w;
#pragma unroll
    for (int m = 1; m <= 8; m <<= 1) ss += __shfl_xor(ss, m);
    const float scale = 1.f / fmaxf(sqrtf(ss), 1e-12f);
    float4 kkv = {kn.x * scale, kn.y * scale, kn.z * scale, kn.w * scale};
    *(float4*)(kkbuf + base) = kkv;
    float4 bb = {kkv.x * av.x, kkv.y * av.y, kkv.z * av.z, kkv.w * av.w};
    *(float4*)(abuf + base) = bb;
    float4 kf = {kr.x * (1.f + (av.x - 1.f) * kav.x),
                 kr.y * (1.f + (av.y - 1.f) * kav.y),
                 kr.z * (1.f + (av.z - 1.f) * kav.z),
                 kr.w * (1.f + (av.w - 1.f) * kav.w)};
    *(float4*)(kbuf + base) = kf;
}

// ---------------------------------------------------------------------------
// Sequential scan, one block per head. 256 threads; thread owns S[v, j0..j0+16)
// with v = tid>>2, j0 = (tid&3)*16. Double-buffered LDS staging, 1 barrier/step.
// S_t = S_{t-1}*ew_j + (S_{t-1}·aa) bb^T + v k^T ;  o = S_t · r
// ---------------------------------------------------------------------------
__global__ __launch_bounds__(256) void scan_kernel(
    const float* __restrict__ rb, const float* __restrict__ ewb,
    const float* __restrict__ kb, const float* __restrict__ vb,
    const float* __restrict__ kkb, const float* __restrict__ bbb,
    const float* __restrict__ init_state, float* __restrict__ y)
{
    const int h = blockIdx.x;
    const int tid = threadIdx.x;
    const int vrow = tid >> 2;
    const int q = tid & 3;
    const int jb = q << 4;
    __shared__ __align__(16) float rs[2][64], ews[2][64], ks[2][64],
                                   vs[2][64], aas[2][64], bbs[2][64];
    float S[16];
    const float* is = init_state + h * 4096 + vrow * 64 + jb;
#pragma unroll
    for (int i = 0; i < 16; ++i) S[i] = is[i];

    const int cb = h * 64;
    const int role = tid >> 6;
    const int lane = tid & 63;

    float p0 = 0.f, p1 = 0.f;
    {
        const int base = cb + lane;   // t = 0
        if (role == 0)      { p0 = rb[base];  p1 = ewb[base]; }
        else if (role == 1) { p0 = kb[base];  p1 = vb[base]; }
        else if (role == 2) { p0 = -kkb[base]; p1 = bbb[base]; }
    }
    if (role == 0)      { rs[0][lane] = p0;  ews[0][lane] = p1; }
    else if (role == 1) { ks[0][lane] = p0;  vs[0][lane]  = p1; }
    else if (role == 2) { aas[0][lane] = p0; bbs[0][lane] = p1; }
    __syncthreads();

    for (int t = 0; t < T_LEN; ++t) {
        const int cur = t & 1, nxt = cur ^ 1;
        if (t + 1 < T_LEN) {   // prefetch next step
            const int base = (t + 1) * C_DIM + cb + lane;
            if (role == 0)      { p0 = rb[base];  p1 = ewb[base]; }
            else if (role == 1) { p0 = kb[base];  p1 = vb[base]; }
            else if (role == 2) { p0 = -kkb[base]; p1 = bbb[base]; }
        }
        float sa = 0.f;
#pragma unroll
        for (int i = 0; i < 16; ++i) sa = fmaf(S[i], aas[cur][jb + i], sa);
        sa += __shfl_xor(sa, 1);
        sa += __shfl_xor(sa, 2);
        const float vv = vs[cur][vrow];
#pragma unroll
        for (int i = 0; i < 16; ++i)
            S[i] = fmaf(vv, ks[cur][jb + i],
                        fmaf(sa, bbs[cur][jb + i], S[i] * ews[cur][jb + i]));
        float o = 0.f;
#pragma unroll
        for (int i = 0; i < 16; ++i) o = fmaf(S[i], rs[cur][jb + i], o);
        o += __shfl_xor(o, 1);
        o += __shfl_xor(o, 2);
        if (q == 0) y[(size_t)t * C_DIM + cb + vrow] = o;
        if (t + 1 < T_LEN) {
            if (role == 0)      { rs[nxt][lane] = p0;  ews[nxt][lane] = p1; }
            else if (role == 1) { ks[nxt][lane] = p0;  vs[nxt][lane]  = p1; }
            else if (role == 2) { aas[nxt][lane] = p0; bbs[nxt][lane] = p1; }
        }
        __syncthreads();
    }
}

// ---------------------------------------------------------------------------
// GroupNorm(eps=0.00064) per (t,head) + bonus + *g.  In-place on y.
// One token per block, 4 channels/thread, 16 threads per head.
// ---------------------------------------------------------------------------
__global__ __launch_bounds__(256) void gn_bonus(
    float* __restrict__ y, const float* __restrict__ rb, const float* __restrict__ kb,
    const float* __restrict__ vb, const float* __restrict__ gb,
    const float* __restrict__ r_k, const float* __restrict__ lnw,
    const float* __restrict__ lnb)
{
    const int t = blockIdx.x, tid = threadIdx.x;
    const int c0 = tid << 2;
    const size_t base = (size_t)t * C_DIM + c0;
    float4 yv = *(float4*)(y + base);
    float sum = yv.x + yv.y + yv.z + yv.w;
    float ss  = yv.x * yv.x + yv.y * yv.y + yv.z * yv.z + yv.w * yv.w;
    float4 rv = *(const float4*)(rb + base);
    float4 kv = *(const float4*)(kb + base);
    float4 rkv = *(const float4*)(r_k + c0);
    float dot = rv.x * kv.x * rkv.x + rv.y * kv.y * rkv.y +
                rv.z * kv.z * rkv.z + rv.w * kv.w * rkv.w;
#pragma unroll
    for (int m = 1; m <= 8; m <<= 1) {
        sum += __shfl_xor(sum, m);
        ss  += __shfl_xor(ss, m);
        dot += __shfl_xor(dot, m);
    }
    const float mu = sum * 0.015625f;
    const float var = ss * 0.015625f - mu * mu;
    const float rstd = rsqrtf(var + 0.00064f);
    float4 wv = *(const float4*)(lnw + c0);
    float4 bv = *(const float4*)(lnb + c0);
    float4 vv = *(const float4*)(vb + base);
    float4 gv = *(const float4*)(gb + base);
    float4 o;
    o.x = ((yv.x - mu) * rstd * wv.x + bv.x + dot * vv.x) * gv.x;
    o.y = ((yv.y - mu) * rstd * wv.y + bv.y + dot * vv.y) * gv.y;
    o.z = ((yv.z - mu) * rstd * wv.z + bv.z + dot * vv.z) * gv.z;
    o.w = ((yv.w - mu) * rstd * wv.w + bv.w + dot * vv.w) * gv.w;
    *(float4*)(y + base) = o;
}

// ---------------------------------------------------------------------------
extern "C" void kernel_launch(void* const* d_in, const int* in_sizes, int n_in,
                              void* d_out, int out_size, void* d_ws, size_t ws_size,
                              hipStream_t stream)
{
    (void)in_sizes; (void)n_in; (void)out_size; (void)ws_size;
    const float* x       = (const float*)d_in[0];
    const float* v_first = (const float*)d_in[1];
    const float* x_prev  = (const float*)d_in[2];
    const float* init_st = (const float*)d_in[3];
    const float* x_r = (const float*)d_in[4];
    const float* x_w = (const float*)d_in[5];
    const float* x_k = (const float*)d_in[6];
    const float* x_v = (const float*)d_in[7];
    const float* x_a = (const float*)d_in[8];
    const float* x_g = (const float*)d_in[9];
    const float* w0  = (const float*)d_in[10];
    const float* a0  = (const float*)d_in[11];
    const float* v0  = (const float*)d_in[12];
    const float* k_k = (const float*)d_in[13];
    const float* k_a = (const float*)d_in[14];
    const float* w1  = (const float*)d_in[15];
    const float* w2  = (const float*)d_in[16];
    const float* a1  = (const float*)d_in[17];
    const float* a2  = (const float*)d_in[18];
    const float* v1  = (const float*)d_in[19];
    const float* v2  = (const float*)d_in[20];
    const float* g1  = (const float*)d_in[21];
    const float* g2  = (const float*)d_in[22];
    const float* r_k = (const float*)d_in[23];
    const float* Wr  = (const float*)d_in[24];
    const float* Wk  = (const float*)d_in[25];
    const float* Wv  = (const float*)d_in[26];
    const float* Wo  = (const float*)d_in[27];
    const float* ln_w = (const float*)d_in[28];
    const float* ln_b = (const float*)d_in[29];

    float* out = (float*)d_out;
    float* ws  = (float*)d_ws;
    const size_t NE = (size_t)T_LEN * C_DIM;
    float* rB  = ws;
    float* ewB = ws + NE;
    float* kB  = ws + 2 * NE;
    float* vB  = ws + 3 * NE;
    float* aB  = ws + 4 * NE;   // a, then bb (in-place)
    float* gB  = ws + 5 * NE;
    float* kkB = ws + 6 * NE;
    float* yB  = ws + 7 * NE;   // scan out, then xo*g (in-place)
    float* hB  = ws + 8 * NE;   // LoRA hidden, T*128 max

    dim3 gg(16, 32);
    gemm_nt<<<gg, 256, 0, stream>>>(x, x_prev, x_r, Wr, rB);
    gemm_nt<<<gg, 256, 0, stream>>>(x, x_prev, x_k, Wk, kB);
    gemm_nt<<<gg, 256, 0, stream>>>(x, x_prev, x_v, Wv, vB);

    // w path: h = tanh(xw@w1); exp(w) = exp(-e^{-0.5} * sigmoid(w0 + h@w2))
    lora1<<<512, 256, 0, stream>>>(x, x_prev, x_w, w1, hB, 64, 1);
    lora2<<<dim3(4, T_LEN), 256, 0, stream>>>(hB, w2, w0, ewB, nullptr, 64, 0);
    // a path: a = sigmoid(a0 + (xa@a1)@a2)
    lora1<<<512, 256, 0, stream>>>(x, x_prev, x_a, a1, hB, 64, 0);
    lora2<<<dim3(4, T_LEN), 256, 0, stream>>>(hB, a2, a0, aB, nullptr, 64, 1);
    // v path: v = v_raw + (v_first - v_raw)*sigmoid(v0 + (xv@v1)@v2)
    lora1<<<256, 256, 0, stream>>>(x, x_prev, x_v, v1, hB, 32, 0);
    lora2<<<dim3(4, T_LEN), 256, 0, stream>>>(hB, v2, v0, vB, v_first, 32, 2);
    // g path: g = sigmoid(xg@g1)@g2
    lora1<<<1024, 256, 0, stream>>>(x, x_prev, x_g, g1, hB, 128, 2);
    lora2<<<dim3(4, T_LEN), 256, 0, stream>>>(hB, g2, nullptr, gB, nullptr, 128, 3);

    kpost<<<T_LEN, 256, 0, stream>>>(kB, aB, kkB, k_k, k_a);
    scan_kernel<<<16, 256, 0, stream>>>(rB, ewB, kB, vB, kkB, aB, init_st, yB);
    gn_bonus<<<T_LEN, 256, 0, stream>>>(yB, rB, kB, vB, gB, r_k, ln_w, ln_b);
    gemm_nt<<<gg, 256, 0, stream>>>(yB, yB, nullptr, Wo, out);
}